// Round 6
// baseline (350.633 us; speedup 1.0000x reference)
//
#include <hip/hip_runtime.h>
#include <math.h>

#define NTOK 65536
#define DIM  64
#define KC   512
#define EPS  0.0625f

typedef _Float16 half8 __attribute__((ext_vector_type(8)));
typedef float    f32x16 __attribute__((ext_vector_type(16)));

// d_ws layout (bytes)
#define WS_COUNTS 0           // int[512]
#define WS_CSQ    2048        // float[512]
#define WS_BPK    4096        // _Float16[512*128]  (per code: ch[64] | cl[64])
#define WS_CANDS  135168      // short[65536][8]: [0]=count or 0x7FFF flag, [1..7]=k

// ---------------------------------------------------------------------------
// Prep: split codebook into fp16 hi/lo + approx csq. 512 blocks x 64.
// ---------------------------------------------------------------------------
__global__ void vq_prep(const float* __restrict__ cb, _Float16* __restrict__ Bpk,
                        float* __restrict__ csqg)
{
    const int k = blockIdx.x, d = threadIdx.x;
    const float c = cb[k * 64 + d];
    const _Float16 hh = (_Float16)c;
    const _Float16 ll = (_Float16)(c - (float)hh);
    Bpk[k * 128 + d]      = hh;
    Bpk[k * 128 + 64 + d] = ll;
    float p = c * c;
    #pragma unroll
    for (int off = 32; off > 0; off >>= 1) p += __shfl_down(p, off);
    if (d == 0) csqg[k] = p;
}

// ---------------------------------------------------------------------------
// Phase 1: MFMA approx distances + candidate lists.
// Block = 256 threads (4 waves); wave = 32 tokens x all 512 codes.
// mfma_f32_32x32x16_f16, 12 per 32-code tile (zh*ch + zl*ch + zh*cl).
// C/D layout (m74/m101-verified): col = lane&31, row = (reg&3)+8*(reg>>2)+4*(lane>>5).
// Tracks per-lane best-1 (d,k) + 2nd-best d; lex (d,k) reduce across the 32
// col-lanes; appends all k within EPS of token min; flag -> full rescan.
// ---------------------------------------------------------------------------
__global__ void vq_dist(const float* __restrict__ z_e, const _Float16* __restrict__ Bpk,
                        const float* __restrict__ csqg, short* __restrict__ candsg)
{
    __shared__ int cnt[128];
    __shared__ int flg[128];
    __shared__ __align__(16) short krec[128][8];

    const int tid = threadIdx.x;
    if (tid < 128) { cnt[tid] = 0; flg[tid] = 0; }
    __syncthreads();

    const int l = tid & 63, w = tid >> 6;
    const int col = l & 31, h = l >> 5;
    const long t = (long)blockIdx.x * 128 + w * 32 + col;

    // ---- A fragments: zh/zl fp16 split of this token's row ----
    half8 azh[4], azl[4];
    #pragma unroll
    for (int c = 0; c < 4; ++c) {
        const float* zp = z_e + t * 64 + c * 16 + h * 8;
        const float4 u0 = *(const float4*)zp;
        const float4 u1 = *(const float4*)(zp + 4);
        const float vv[8] = {u0.x, u0.y, u0.z, u0.w, u1.x, u1.y, u1.z, u1.w};
        half8 zh, zl;
        #pragma unroll
        for (int i = 0; i < 8; ++i) {
            const _Float16 hh = (_Float16)vv[i];
            zh[i] = hh;
            zl[i] = (_Float16)(vv[i] - (float)hh);
        }
        azh[c] = zh; azl[c] = zl;
    }

    float b1[16], b2[16];
    int   k1[16];
    #pragma unroll
    for (int j = 0; j < 16; ++j) { b1[j] = INFINITY; b2[j] = INFINITY; k1[j] = 0; }

    f32x16 zerov;
    #pragma unroll
    for (int j = 0; j < 16; ++j) zerov[j] = 0.0f;

    const _Float16* bbase = Bpk + (size_t)col * 128 + h * 8;

    for (int nt = 0; nt < 16; ++nt) {
        const int n0 = nt * 32;
        const _Float16* bp = bbase + (size_t)n0 * 128;
        half8 bch[4], bcl[4];
        #pragma unroll
        for (int c = 0; c < 4; ++c) {
            bch[c] = *(const half8*)(bp + c * 16);
            bcl[c] = *(const half8*)(bp + 64 + c * 16);
        }
        const float csql = csqg[n0 + col];

        f32x16 acc = __builtin_amdgcn_mfma_f32_32x32x16_f16(azh[0], bch[0], zerov, 0, 0, 0);
        #pragma unroll
        for (int c = 1; c < 4; ++c)
            acc = __builtin_amdgcn_mfma_f32_32x32x16_f16(azh[c], bch[c], acc, 0, 0, 0);
        #pragma unroll
        for (int c = 0; c < 4; ++c)
            acc = __builtin_amdgcn_mfma_f32_32x32x16_f16(azl[c], bch[c], acc, 0, 0, 0);
        #pragma unroll
        for (int c = 0; c < 4; ++c)
            acc = __builtin_amdgcn_mfma_f32_32x32x16_f16(azh[c], bcl[c], acc, 0, 0, 0);

        const int kk = n0 + col;
        #pragma unroll
        for (int j = 0; j < 16; ++j) {
            const float d = fmaf(acc[j], -2.0f, csql);   // csq - 2*dot (zsq shift-invariant)
            const bool lt = d < b1[j];
            b2[j] = lt ? b1[j] : fminf(b2[j], d);
            k1[j] = lt ? kk : k1[j];
            b1[j] = lt ? d : b1[j];
        }
    }

    // ---- per-token lex-min reduce over the 32 col-lanes + candidate append ----
    #pragma unroll
    for (int j = 0; j < 16; ++j) {
        float d = b1[j];
        int   k = k1[j];
        #pragma unroll
        for (int m = 1; m <= 16; m <<= 1) {
            const float od = __shfl_xor(d, m);
            const int   ok = __shfl_xor(k, m);
            const bool bet = (od < d) || (od == d && ok < k);
            d = bet ? od : d;
            k = bet ? ok : k;
        }
        const int tokl = w * 32 + (j & 3) + 8 * (j >> 2) + 4 * h;
        if (b1[j] < d + EPS) {
            const int idx = atomicAdd(&cnt[tokl], 1);
            if (idx < 7) krec[tokl][1 + idx] = (short)k1[j];
            else flg[tokl] = 1;
        }
        if (b2[j] < d + EPS) flg[tokl] = 1;   // unrecorded 2nd-in-lane near min
    }
    __syncthreads();

    if (tid < 128) {
        const int c = cnt[tid];
        const bool f = (flg[tid] != 0) || (c > 7);
        krec[tid][0] = f ? (short)0x7FFF : (short)c;
        const long tok = (long)blockIdx.x * 128 + tid;
        ((int4*)candsg)[tok] = *(int4*)&krec[tid][0];
    }
}

// ---------------------------------------------------------------------------
// Phase 2: exact f32 refinement of candidates (r2-verbatim arithmetic) +
// all outputs. Block = 64 tokens, 256 threads; 4 lanes per token split dims.
// ---------------------------------------------------------------------------
__global__ void vq_refine(const float* __restrict__ z_e, const float* __restrict__ cb,
                          const short* __restrict__ candsg,
                          float* __restrict__ z_q, float* __restrict__ qzx,
                          float* __restrict__ e_k, int* __restrict__ counts)
{
    __shared__ float zs[64][65];
    __shared__ int   kwin[64];
    __shared__ int   hist[KC];

    const int tid = threadIdx.x;
    const long tok0 = (long)blockIdx.x * 64;

    hist[tid] = 0;
    hist[tid + 256] = 0;

    // stage z (coalesced, r2 verbatim)
    {
        const float4* zg = (const float4*)(z_e + tok0 * 64);
        #pragma unroll
        for (int it = 0; it < 4; ++it) {
            const int f4 = it * 256 + tid;
            const float4 v = zg[f4];
            const int row = f4 >> 4;
            const int c4  = (f4 & 15) << 2;
            zs[row][c4 + 0] = v.x; zs[row][c4 + 1] = v.y;
            zs[row][c4 + 2] = v.z; zs[row][c4 + 3] = v.w;
        }
    }
    __syncthreads();

    const int g = tid >> 2, sub = tid & 3;

    // zsq partial (r2 chain: s_j over dims 16j..16j+15, then (s0+s1)+(s2+s3))
    float s = 0.f;
    #pragma unroll
    for (int d = 0; d < 16; ++d) { const float zv = zs[g][16 * sub + d]; s += zv * zv; }
    const float spair = s + __shfl_xor(s, 1);
    const float zsq   = spair + __shfl_xor(spair, 2);

    const int4 rc = ((const int4*)candsg)[tok0 + g];
    const short* rp = (const short*)&rc;
    const int cw = rp[0];
    const int nc = (cw == 0x7FFF) ? KC : cw;

    float dm = INFINITY;
    int   km = 0;
    for (int i = 0; i < nc; ++i) {
        const int k = (cw == 0x7FFF) ? i : (int)rp[1 + i];
        const float4* cf = (const float4*)(cb + (size_t)k * 64 + 16 * sub);
        float a = 0.f, q = 0.f;
        #pragma unroll
        for (int j = 0; j < 4; ++j) {
            const float4 v = cf[j];
            a = fmaf(zs[g][16 * sub + 4 * j + 0], v.x, a);
            a = fmaf(zs[g][16 * sub + 4 * j + 1], v.y, a);
            a = fmaf(zs[g][16 * sub + 4 * j + 2], v.z, a);
            a = fmaf(zs[g][16 * sub + 4 * j + 3], v.w, a);
            q += v.x * v.x + v.y * v.y + v.z * v.z + v.w * v.w;
        }
        const float ap  = a + __shfl_xor(a, 1);
        const float dot = ap + __shfl_xor(ap, 2);
        const float qp  = q + __shfl_xor(q, 1);
        const float csq = qp + __shfl_xor(qp, 2);
        const float dist = (zsq - 2.0f * dot) + csq;     // r2 formula order
        const bool bet = (dist < dm) || (dist == dm && k < km);
        dm = bet ? dist : dm;
        km = bet ? k : km;
    }
    if (sub == 0) kwin[g] = km;
    __syncthreads();

    if (tid < 64) {
        const int k2 = kwin[tid];
        atomicAdd(&hist[k2], 1);
        qzx[tok0 + tid] = (float)k2;
    }
    __syncthreads();

    atomicAdd(&counts[tid],       hist[tid]);
    atomicAdd(&counts[tid + 256], hist[tid + 256]);

    // e_k / z_q coalesced epilogue (r2 verbatim)
    {
        float4* eo = (float4*)(e_k + tok0 * 64);
        float4* zo = (float4*)(z_q + tok0 * 64);
        #pragma unroll
        for (int it = 0; it < 4; ++it) {
            const int f4  = it * 256 + tid;
            const int row = f4 >> 4;
            const int c4  = (f4 & 15) << 2;
            const int kmr = kwin[row];
            const float4 cv = ((const float4*)(cb + (size_t)kmr * 64))[f4 & 15];
            float4 zv;
            zv.x = zs[row][c4 + 0]; zv.y = zs[row][c4 + 1];
            zv.z = zs[row][c4 + 2]; zv.w = zs[row][c4 + 3];
            float4 qq;
            qq.x = zv.x + (cv.x - zv.x);
            qq.y = zv.y + (cv.y - zv.y);
            qq.z = zv.z + (cv.z - zv.z);
            qq.w = zv.w + (cv.w - zv.w);
            eo[f4] = cv;
            zo[f4] = qq;
        }
    }
}

// ---------------------------------------------------------------------------
// Perplexity (unchanged, proven)
// ---------------------------------------------------------------------------
__global__ void vq_perp(const int* __restrict__ counts, float* __restrict__ perp)
{
    const int tid = threadIdx.x;
    const float p = (float)counts[tid] * (1.0f / 65536.0f);
    float s = p * logf(p + 1e-10f);
    #pragma unroll
    for (int off = 32; off > 0; off >>= 1) s += __shfl_down(s, off);
    __shared__ float red[8];
    if ((tid & 63) == 0) red[tid >> 6] = s;
    __syncthreads();
    if (tid == 0) {
        float tot = 0.f;
        #pragma unroll
        for (int j = 0; j < 8; ++j) tot += red[j];
        perp[0] = expf(-tot);
    }
}

extern "C" void kernel_launch(void* const* d_in, const int* in_sizes, int n_in,
                              void* d_out, int out_size, void* d_ws, size_t ws_size,
                              hipStream_t stream)
{
    const float* z_e = (const float*)d_in[0];
    const float* cb  = (const float*)d_in[1];

    float* out  = (float*)d_out;
    float* z_q  = out;
    float* qzx  = out + (size_t)NTOK * DIM;
    float* e_k  = qzx + NTOK;
    float* perp = e_k + (size_t)NTOK * DIM;

    char* ws = (char*)d_ws;
    int*      counts = (int*)(ws + WS_COUNTS);
    float*    csqg   = (float*)(ws + WS_CSQ);
    _Float16* Bpk    = (_Float16*)(ws + WS_BPK);
    short*    cands  = (short*)(ws + WS_CANDS);

    hipMemsetAsync(counts, 0, KC * sizeof(int), stream);
    vq_prep<<<KC, 64, 0, stream>>>(cb, Bpk, csqg);
    vq_dist<<<NTOK / 128, 256, 0, stream>>>(z_e, Bpk, csqg, cands);
    vq_refine<<<NTOK / 64, 256, 0, stream>>>(z_e, cb, cands, z_q, qzx, e_k, counts);
    vq_perp<<<1, KC, 0, stream>>>(counts, perp);
}